// Round 2
// baseline (429.268 us; speedup 1.0000x reference)
//
#include <hip/hip_runtime.h>

// conv2d NCHW/OIHW, stride 1, VALID. x=(64,3,256,256) f32, w=(16,3,3,3), b=(16)
// out=(64,16,254,254) f32.  Memory floor: 264 MB write + 50 MB read ~= 50 us.
//
// R1 restructure: weights staged in LDS (transposed to [c][kh][kw][oc] so a
// 4-oc group is one ds_read_b128). Each thread: 8 consecutive ow pixels x
// 4 oc = 32 outputs, 32 VGPR accumulators. Weight reads: 27 b128/thread
// (vs ~432 scalar re-loads in R0 -- the stall source). Input: aligned float4.

constexpr int N = 64, C = 3, H = 256, W = 256;
constexpr int OC = 16, K = 3, OH = 254, OW = 254;
constexpr int PX = 8;            // pixels per thread
constexpr int NWU = 32;          // ceil(OW/PX): 8-px units per row (unit 31 partial)
constexpr int NG = 4;            // oc groups of 4

__global__ __launch_bounds__(256) void conv3x3_kernel(
    const float* __restrict__ x, const float* __restrict__ w,
    const float* __restrict__ bias, float* __restrict__ out)
{
    // ---- stage weights (transposed) + bias into LDS ----
    __shared__ float lw[C * K * K * OC + OC];   // 432 + 16 floats
    int t = threadIdx.x;
    for (int i = t; i < C * K * K * OC; i += 256) {
        int oc = i & 15, r = i >> 4;            // r = c*9 + kh*3 + kw
        int kw = r % 3, kh = (r / 3) % 3, c = r / 9;
        lw[i] = w[oc * 27 + c * 9 + kh * 3 + kw];
    }
    if (t < OC) lw[C * K * K * OC + t] = bias[t];
    __syncthreads();

    // ---- thread mapping: idx -> (n, oh, g, owu); lanes consecutive in owu ----
    int idx = blockIdx.x * 256 + t;             // grid sized exactly, no tail
    int owu = idx & (NWU - 1);
    int g   = (idx >> 5) & (NG - 1);
    int rr  = idx >> 7;
    int oh  = rr % OH;
    int n   = rr / OH;
    int ow0 = owu * PX;

    // ---- accumulators: acc[px][oc_in_group], init with bias ----
    float accv[PX][4];
    {
        const float* bv = &lw[C * K * K * OC + 4 * g];
        float b0 = bv[0], b1 = bv[1], b2 = bv[2], b3 = bv[3];
        #pragma unroll
        for (int j = 0; j < PX; ++j) {
            accv[j][0] = b0; accv[j][1] = b1; accv[j][2] = b2; accv[j][3] = b3;
        }
    }

    const float* xb = x + ((size_t)n * C * H + oh) * W + ow0;
    bool full = (ow0 + 10 <= W);                // false only for owu == 31

    #pragma unroll
    for (int c = 0; c < C; ++c) {
        #pragma unroll
        for (int kh = 0; kh < K; ++kh) {
            const float* xr = xb + ((size_t)c * H + kh) * W;
            // 10 input columns cover 8 pixels' 3-wide windows (aligned f4 x2)
            float4 xa = *reinterpret_cast<const float4*>(xr);
            float4 xc = *reinterpret_cast<const float4*>(xr + 4);
            float x8 = full ? xr[8] : 0.f;      // cols 256/257 would be OOB on
            float x9 = full ? xr[9] : 0.f;      // the last row -- predicated
            float xx[10] = {xa.x, xa.y, xa.z, xa.w, xc.x, xc.y, xc.z, xc.w, x8, x9};

            const float* wp = &lw[(c * 9 + kh * 3) * 16 + 4 * g];
            #pragma unroll
            for (int kw = 0; kw < K; ++kw) {
                // one b128 = weights for this tap across the 4-oc group
                float4 wv = *reinterpret_cast<const float4*>(wp + kw * 16);
                #pragma unroll
                for (int j = 0; j < PX; ++j) {
                    float xi = xx[j + kw];
                    accv[j][0] += xi * wv.x;
                    accv[j][1] += xi * wv.y;
                    accv[j][2] += xi * wv.z;
                    accv[j][3] += xi * wv.w;
                }
            }
        }
    }

    // ---- store: 4 oc planes x 4 float2 pairs (8B-aligned always) ----
    float* ob = out + ((size_t)(n * OC + g * 4) * OH + oh) * OW + ow0;
    #pragma unroll
    for (int q = 0; q < 4; ++q) {
        float* oq = ob + (size_t)q * OH * OW;
        #pragma unroll
        for (int p = 0; p < 4; ++p) {
            if (ow0 + 2 * p < OW) {             // pair-granular edge mask (OW even)
                float2 v = make_float2(accv[2 * p][q], accv[2 * p + 1][q]);
                *reinterpret_cast<float2*>(oq + 2 * p) = v;
            }
        }
    }
}

extern "C" void kernel_launch(void* const* d_in, const int* in_sizes, int n_in,
                              void* d_out, int out_size, void* d_ws, size_t ws_size,
                              hipStream_t stream) {
    const float* x    = (const float*)d_in[0];
    const float* w    = (const float*)d_in[1];
    const float* bias = (const float*)d_in[2];
    float* out        = (float*)d_out;

    constexpr int total  = N * OH * NG * NWU;   // 2,080,768 = 8128 * 256 exactly
    constexpr int block  = 256;
    constexpr int blocks = total / block;
    conv3x3_kernel<<<blocks, block, 0, stream>>>(x, w, bias, out);
}